// Round 15
// baseline (302.309 us; speedup 1.0000x reference)
//
#include <hip/hip_runtime.h>
#include <float.h>
#include <math.h>

#define D 512
#define VDIM 512
#define KSEL 32
#define BM 256
#define BN 256
#define CAP 2048
#define TSEL 48
#define SELMAX 128
#define TAU 0.11f
#define ROWSLOTS 16

typedef int i32x4 __attribute__((ext_vector_type(4)));
typedef const unsigned int __attribute__((address_space(1))) as1_uint;
typedef unsigned int __attribute__((address_space(3))) as3_uint;

// ---------- Kernel 1: norms + normalized-i8 quantization (1 wave/row) ------
__global__ __launch_bounds__(256)
void k_prep(const float* __restrict__ queries, const float* __restrict__ keys,
            signed char* __restrict__ qi8, signed char* __restrict__ ki8,
            float* __restrict__ inv_nq, float* __restrict__ inv_nk,
            float* __restrict__ sq, float* __restrict__ sk, int B, int N) {
  const int wid = threadIdx.x >> 6, lane = threadIdx.x & 63;
  const int row = blockIdx.x * 4 + wid;
  if (row >= N + B) return;
  const bool iskey = row < N;
  const float* src = iskey ? keys + (size_t)row * D : queries + (size_t)(row - N) * D;
  float4 f0 = *(const float4*)(src + lane * 8);
  float4 f1 = *(const float4*)(src + lane * 8 + 4);
  float sc[8] = {f0.x, f0.y, f0.z, f0.w, f1.x, f1.y, f1.z, f1.w};
  float ss = 0.f, ma = 0.f;
  #pragma unroll
  for (int e = 0; e < 8; ++e) { ss += sc[e] * sc[e]; ma = fmaxf(ma, fabsf(sc[e])); }
  #pragma unroll
  for (int off = 32; off; off >>= 1) {
    ss += __shfl_xor(ss, off);
    ma = fmaxf(ma, __shfl_xor(ma, off));
  }
  const float inv = 1.0f / fmaxf(sqrtf(ss), 1e-8f);
  const float qmul = 127.0f / ma;
  const float qs = ma * inv * (1.0f / 127.0f);
  union { signed char c[8]; long long l; } pk;
  #pragma unroll
  for (int e = 0; e < 8; ++e) {
    int qv = __float2int_rn(sc[e] * qmul);
    qv = max(-127, min(127, qv));
    pk.c[e] = (signed char)qv;
  }
  signed char* dst = (iskey ? ki8 + (size_t)row * D
                            : qi8 + (size_t)(row - N) * D) + lane * 8;
  *(long long*)dst = pk.l;
  if (lane == 0) {
    if (iskey) { inv_nk[row] = inv; sk[row] = qs; }
    else       { inv_nq[row - N] = inv; sq[row - N] = qs; }
  }
}

// ---------- Kernel 2: i8 MFMA sims + threshold compaction -------------------
// 256x256 tile, 1024 threads (16 waves 4Mx4N), ring-2 x 32KB = 64KB LDS.
// Both proven levers at once: blocks 6256 -> 3128 (fixed cost amortized over
// 2x FLOPs) AND 2 blocks/CU co-resident at VGPR<=64 (R14 measured 56 with the
// identical per-wave register content: acc[4][4] i32, a[4], b[4]).
// Per-wave phase shape unchanged vs R13/R14: 8 ds_read_b128 + 16 MFMA per
// phase, 8 phases, free-wait __syncthreads ring-2 (4 schedule families proved
// wait structure immaterial). Decode = R8's 16KB/256-row form (1 instr at
// 1024 thr); swizzle algebra byte-identical. Epilogue = R6 two-level, 256 rows.
__global__ __launch_bounds__(1024)
void k_gemm_filter(const signed char* __restrict__ qi8,
                   const signed char* __restrict__ ki8,
                   const float* __restrict__ sq, const float* __restrict__ sk,
                   float* __restrict__ cand, int* __restrict__ gcnt,
                   int B, int N) {
  __shared__ char lds[2 * 32768];   // 2 ring slots x [A 16KB | B 16KB]
  const int t = threadIdx.x;
  const int lane = t & 63, wid = t >> 6;
  const int wr = wid >> 2, wc = wid & 3;        // 4 x 4 wave grid
  const int lr = lane & 15, lg = lane >> 4;

  const int nq = B / BM;                 // 8
  const int nk = (N + BN - 1) / BN;      // 391
  const int nwg = nq * nk;               // 3128 (divisible by 8)
  const int bid = blockIdx.x;
  // bijective XCD chunk swizzle (m204)
  const int qq = nwg >> 3, rr = nwg & 7;
  const int xcd = bid & 7, idx = bid >> 3;
  const int swz = (xcd < rr ? xcd * (qq + 1) : rr * (qq + 1) + (xcd - rr) * qq) + idx;
  const int qt = swz % nq, ktile = swz / nq;
  const int qbase = qt * BM;
  const int tile = ktile * BN;

  // --- staging precompute: linear LDS byte -> (logical row, chunk) ---
  // each 16KB region covered by ONE gload instr: lb = t*16 (1024 thr x 16B).
  const char* gA1; const char* gB1; int ldA1, ldB1;
  {
    int lb = t * 16;
    int R = lb >> 7, s = (lb >> 4) & 7;
    int cr = s ^ (R & 7);
    int r = 2 * R + ((cr >> 2) & 1);     // logical row 0..255
    int c = cr & 3;                      // 16B chunk (16 i8 k-elems)
    gA1 = (const char*)qi8 + (size_t)(qbase + r) * D + c * 16;
    gB1 = (const char*)ki8 + (size_t)min(tile + r, N - 1) * D + c * 16;
    ldA1 = wid * 1024;                   // + slot*32768
    ldB1 = 16384 + wid * 1024;           // + slot*32768
  }

  // --- ds_read lane constants (same swizzle algebra as R8/R11/R13/R14) ---
  const int laneByte = (lr >> 1) * 128 + (((lg + 4 * (lr & 1)) ^ ((lr >> 1) & 7)) * 16);
  const int aWaveOff = wr * 4096;          // + m*1024 (wr steps of 64 rows)
  const int bWaveOff = 16384 + wc * 4096;  // + n*1024

  i32x4 acc[4][4];
  #pragma unroll
  for (int m = 0; m < 4; ++m)
    #pragma unroll
    for (int n = 0; n < 4; ++n) acc[m][n] = (i32x4)0;

  auto STAGE = [&](int u, int slot) {   // one unit (K=64): 2 gloads/thread
    const int off = u * 64;             // 64 k-elems * 1B
    const int dbase = slot * 32768;
    __builtin_amdgcn_global_load_lds((as1_uint*)(const void*)(gA1 + off),
                                     (as3_uint*)(void*)(lds + dbase + ldA1), 16, 0, 0);
    __builtin_amdgcn_global_load_lds((as1_uint*)(const void*)(gB1 + off),
                                     (as3_uint*)(void*)(lds + dbase + ldB1), 16, 0, 0);
  };

  STAGE(0, 0);                           // prologue

  #pragma unroll 1
  for (int u = 0; u < 8; ++u) {        // 8 phases, K=64 each
    const int slot = u & 1;
    __syncthreads();                   // free wait: unit u issued a phase ago
    STAGE((u + 1) & 7, slot ^ 1);      // u=7 dummy-stages unit 0
    const char* abase = lds + slot * 32768 + aWaveOff + laneByte;
    const char* bbase = lds + slot * 32768 + bWaveOff + laneByte;
    i32x4 a[4], b[4];
    #pragma unroll
    for (int m = 0; m < 4; ++m) a[m] = *(const i32x4*)(abase + m * 1024);
    #pragma unroll
    for (int n = 0; n < 4; ++n) b[n] = *(const i32x4*)(bbase + n * 1024);
    __builtin_amdgcn_s_setprio(1);
    #pragma unroll
    for (int m = 0; m < 4; ++m)
      #pragma unroll
      for (int n = 0; n < 4; ++n)
        acc[m][n] = __builtin_amdgcn_mfma_i32_16x16x64_i8(a[m], b[n], acc[m][n], 0, 0, 0);
    __builtin_amdgcn_s_setprio(0);
  }

  // ---- epilogue: dequant + two-level compaction of sims >= TAU ----
  __syncthreads();   // drains vmcnt(0) before LDS reuse
  unsigned int* rowcnt = (unsigned int*)lds;                 // 256 x u32 (1KB)
  float2* rowlist = (float2*)(lds + 1024);                   // 256 x 16 x 8B (32KB)
  float* sQl = (float*)(lds + 1024 + 32768);                 // 256 floats
  float* sKl = (float*)(lds + 1024 + 32768 + 1024);          // 256 floats
  if (t < BM) { rowcnt[t] = 0; sQl[t] = sq[qbase + t]; }
  else if (t < 512) sKl[t - 256] = sk[min(tile + t - 256, N - 1)];
  __syncthreads();
  // C/D layout: col=lane&15 (lr), row=(lane>>4)*4+reg (lg*4+j)
  float skv[4];
  #pragma unroll
  for (int n = 0; n < 4; ++n) skv[n] = sKl[wc * 64 + n * 16 + lr];
  #pragma unroll
  for (int m = 0; m < 4; ++m) {
    #pragma unroll
    for (int j = 0; j < 4; ++j) {
      int rl = wr * 64 + m * 16 + lg * 4 + j;   // local query row 0..255
      const float sqv = sQl[rl];
      #pragma unroll
      for (int n = 0; n < 4; ++n) {
        int cl = wc * 64 + n * 16 + lr;         // local key col 0..255
        float v = (float)acc[m][n][j] * (sqv * skv[n]);
        int kg = tile + cl;
        if (v >= TAU && kg < N) {
          unsigned int p = atomicAdd(&rowcnt[rl], 1u);
          if (p < ROWSLOTS) {
            float2 e; e.x = v; e.y = __int_as_float(kg);
            rowlist[rl * ROWSLOTS + p] = e;
          }
        }
      }
    }
  }
  __syncthreads();
  if (t < BM) {
    unsigned int cnt = rowcnt[t];
    if (cnt > ROWSLOTS) cnt = ROWSLOTS;
    if (cnt) {
      int qg = qbase + t;
      int pos = atomicAdd(&gcnt[qg], (int)cnt);
      #pragma unroll 1
      for (unsigned int i = 0; i < cnt; ++i) {
        if (pos + (int)i < CAP)
          *(float2*)&cand[((size_t)qg * CAP + pos + i) * 2] = rowlist[t * ROWSLOTS + i];
      }
    }
  }
}

// ---------- Kernel 3: threshold-select -> exact rescore -> output -----------
__global__ __launch_bounds__(256)
void k_merge_rescore(const float* __restrict__ cand, const int* __restrict__ gcnt,
                     const float* __restrict__ queries, const float* __restrict__ keys,
                     const float* __restrict__ values,
                     const float* __restrict__ inv_nq, const float* __restrict__ inv_nk,
                     float* __restrict__ out, int B, int N) {
  __shared__ float cv[CAP]; __shared__ int ci[CAP];
  __shared__ float qrow[D];
  __shared__ int wcnt[4];
  __shared__ int sel[SELMAX]; __shared__ float exacts[SELMAX];
  __shared__ unsigned int selcnt;
  __shared__ float topv[KSEL]; __shared__ int topi[KSEL];
  __shared__ float wts[KSEL]; __shared__ float inv_sum_s;
  const int t = threadIdx.x, lane = t & 63, wid = t >> 6;
  const int q = blockIdx.x;
  const int cnt = min(gcnt[q], CAP);
  for (int p = t; p < D; p += 256) qrow[p] = queries[(size_t)q * D + p];
  for (int p = t; p < cnt; p += 256) {
    float2 e = *(const float2*)&cand[((size_t)q * CAP + p) * 2];
    cv[p] = e.x; ci[p] = __float_as_int(e.y);
  }
  if (t == 0) selcnt = 0u;
  __syncthreads();
  // threshold binary search (all threads compute identical lo/hi trajectory)
  float thr = -FLT_MAX;
  if (cnt > TSEL) {
    float lo = TAU, hi = 1.03f;
    for (int it = 0; it < 12; ++it) {
      float mid = 0.5f * (lo + hi);
      int c = 0;
      for (int p = t; p < cnt; p += 256) c += (cv[p] >= mid);
      #pragma unroll
      for (int off = 32; off; off >>= 1) c += __shfl_xor(c, off);
      if (lane == 0) wcnt[wid] = c;
      __syncthreads();
      int tot = wcnt[0] + wcnt[1] + wcnt[2] + wcnt[3];
      if (tot >= TSEL) lo = mid; else hi = mid;
      __syncthreads();
    }
    thr = lo;
  }
  // collect candidate set >= thr
  for (int p = t; p < cnt; p += 256) {
    if (cv[p] >= thr) {
      unsigned int s = atomicAdd(&selcnt, 1u);
      if (s < SELMAX) sel[s] = ci[p];
    }
  }
  __syncthreads();
  const int M = min((int)selcnt, SELMAX);
  // exact fp32 rescore of all M rows (wave-per-row)
  const float invq = inv_nq[q];
  #pragma unroll 1
  for (int j = wid; j < M; j += 4) {
    int idx = sel[j];
    const float4* kr = (const float4*)(keys + (size_t)idx * D);
    float4 k0 = kr[lane * 2], k1 = kr[lane * 2 + 1];
    float4 q0 = *(const float4*)&qrow[lane * 8];
    float4 q1 = *(const float4*)&qrow[lane * 8 + 4];
    float dotv = q0.x*k0.x + q0.y*k0.y + q0.z*k0.z + q0.w*k0.w
               + q1.x*k1.x + q1.y*k1.y + q1.z*k1.z + q1.w*k1.w;
    #pragma unroll
    for (int off = 32; off; off >>= 1) dotv += __shfl_xor(dotv, off);
    if (lane == 0) exacts[j] = dotv * invq * inv_nk[idx];
  }
  __syncthreads();
  // exact sorted top-32 from M (<=128): wave 0, 2 values/lane
  if (wid == 0) {
    float v0 = (lane < M) ? exacts[lane] : -FLT_MAX;
    float v1 = (lane + 64 < M) ? exacts[lane + 64] : -FLT_MAX;
    const int p0 = lane, p1 = lane + 64;
    for (int r = 0; r < KSEL; ++r) {
      float bv; int bp;
      if (v0 >= v1) { bv = v0; bp = p0; } else { bv = v1; bp = p1; }
      #pragma unroll
      for (int off = 32; off; off >>= 1) {
        float ov = __shfl_xor(bv, off); int op = __shfl_xor(bp, off);
        if (ov > bv || (ov == bv && op < bp)) { bv = ov; bp = op; }
      }
      if (lane == 0) { topv[r] = bv; topi[r] = sel[bp]; }
      if (p0 == bp) v0 = -FLT_MAX;
      if (p1 == bp) v1 = -FLT_MAX;
    }
  }
  __syncthreads();
  if (t == 0) {
    float mx = topv[0], sum = 0.f;
    for (int r = 0; r < KSEL; ++r) { float w = expf(topv[r] - mx); wts[r] = w; sum += w; }
    inv_sum_s = 1.0f / sum;
  }
  __syncthreads();
  const float inv_sum = inv_sum_s;
  float a0 = 0.f, a1 = 0.f;
  #pragma unroll 1
  for (int r = 0; r < KSEL; ++r) {
    const float* vr = values + (size_t)topi[r] * VDIM;
    float w = wts[r];
    a0 += w * vr[t]; a1 += w * vr[t + 256];
  }
  out[(size_t)q * VDIM + t] = a0 * inv_sum;
  out[(size_t)q * VDIM + t + 256] = a1 * inv_sum;
  if (t < KSEL) out[(size_t)B * VDIM + (size_t)q * KSEL + t] = topv[t];
}

extern "C" void kernel_launch(void* const* d_in, const int* in_sizes, int n_in,
                              void* d_out, int out_size, void* d_ws, size_t ws_size,
                              hipStream_t stream) {
  const float* queries = (const float*)d_in[0];
  const float* keys    = (const float*)d_in[1];
  const float* values  = (const float*)d_in[2];
  const int B = in_sizes[0] / D;     // 2048
  const int N = in_sizes[1] / D;     // 100000
  char* ws = (char*)d_ws;
  size_t o = 0;
  signed char* ki8 = (signed char*)(ws + o); o += (size_t)N * D; o = (o + 255) & ~(size_t)255;
  signed char* qi8 = (signed char*)(ws + o); o += (size_t)B * D; o = (o + 255) & ~(size_t)255;
  float* inv_nk = (float*)(ws + o); o += (size_t)N * 4; o = (o + 255) & ~(size_t)255;
  float* inv_nq = (float*)(ws + o); o += (size_t)B * 4; o = (o + 255) & ~(size_t)255;
  float* sk     = (float*)(ws + o); o += (size_t)N * 4; o = (o + 255) & ~(size_t)255;
  float* sq     = (float*)(ws + o); o += (size_t)B * 4; o = (o + 255) & ~(size_t)255;
  int*   gcnt   = (int*)(ws + o);   o += (size_t)B * 4; o = (o + 255) & ~(size_t)255;
  float* cand   = (float*)(ws + o); o += (size_t)B * CAP * 8;
  float* out = (float*)d_out;

  hipMemsetAsync(gcnt, 0, B * sizeof(int), stream);
  k_prep<<<(N + B + 3) / 4, 256, 0, stream>>>(queries, keys, qi8, ki8,
                                              inv_nq, inv_nk, sq, sk, B, N);
  const int nq = B / BM, nk = (N + BN - 1) / BN;
  k_gemm_filter<<<nq * nk, 1024, 0, stream>>>(qi8, ki8, sq, sk, cand, gcnt, B, N);
  k_merge_rescore<<<B, 256, 0, stream>>>(cand, gcnt, queries, keys, values,
                                         inv_nq, inv_nk, out, B, N);
}

// Round 16
// 291.329 us; speedup vs baseline: 1.0377x; 1.0377x over previous
//
#include <hip/hip_runtime.h>
#include <float.h>
#include <math.h>

#define D 512
#define VDIM 512
#define KSEL 32
#define BM 128
#define BN 256
#define CAP 2048
#define TSEL 48
#define SELMAX 128
#define TAU 0.11f
#define ROWSLOTS 16

typedef int i32x4 __attribute__((ext_vector_type(4)));
typedef const unsigned int __attribute__((address_space(1))) as1_uint;
typedef unsigned int __attribute__((address_space(3))) as3_uint;

// ---------- Kernel 1: norms + normalized-i8 quantization (1 wave/row) ------
__global__ __launch_bounds__(256)
void k_prep(const float* __restrict__ queries, const float* __restrict__ keys,
            signed char* __restrict__ qi8, signed char* __restrict__ ki8,
            float* __restrict__ inv_nq, float* __restrict__ inv_nk,
            float* __restrict__ sq, float* __restrict__ sk, int B, int N) {
  const int wid = threadIdx.x >> 6, lane = threadIdx.x & 63;
  const int row = blockIdx.x * 4 + wid;
  if (row >= N + B) return;
  const bool iskey = row < N;
  const float* src = iskey ? keys + (size_t)row * D : queries + (size_t)(row - N) * D;
  float4 f0 = *(const float4*)(src + lane * 8);
  float4 f1 = *(const float4*)(src + lane * 8 + 4);
  float sc[8] = {f0.x, f0.y, f0.z, f0.w, f1.x, f1.y, f1.z, f1.w};
  float ss = 0.f, ma = 0.f;
  #pragma unroll
  for (int e = 0; e < 8; ++e) { ss += sc[e] * sc[e]; ma = fmaxf(ma, fabsf(sc[e])); }
  #pragma unroll
  for (int off = 32; off; off >>= 1) {
    ss += __shfl_xor(ss, off);
    ma = fmaxf(ma, __shfl_xor(ma, off));
  }
  const float inv = 1.0f / fmaxf(sqrtf(ss), 1e-8f);
  const float qmul = 127.0f / ma;
  const float qs = ma * inv * (1.0f / 127.0f);
  union { signed char c[8]; long long l; } pk;
  #pragma unroll
  for (int e = 0; e < 8; ++e) {
    int qv = __float2int_rn(sc[e] * qmul);
    qv = max(-127, min(127, qv));
    pk.c[e] = (signed char)qv;
  }
  signed char* dst = (iskey ? ki8 + (size_t)row * D
                            : qi8 + (size_t)(row - N) * D) + lane * 8;
  *(long long*)dst = pk.l;
  if (lane == 0) {
    if (iskey) { inv_nk[row] = inv; sk[row] = qs; }
    else       { inv_nq[row - N] = inv; sq[row - N] = qs; }
  }
}

// ---------- Kernel 2: i8 MFMA sims + threshold compaction -------------------
// R14 geometry VERBATIM (verified 171us, the plateau of the occupancy ladder
// 254->231->198->171; R15's 1024-thr variant was null). 128x256 tile, 512
// threads (8 waves 2Mx4N), ring-2 x 24KB = 48KB LDS, free-wait ring-2,
// 8 phases of {8 ds_read_b128 + 16 MFMA}, R6 two-level compaction epilogue.
__global__ __launch_bounds__(512)
void k_gemm_filter(const signed char* __restrict__ qi8,
                   const signed char* __restrict__ ki8,
                   const float* __restrict__ sq, const float* __restrict__ sk,
                   float* __restrict__ cand, int* __restrict__ gcnt,
                   int B, int N) {
  __shared__ char lds[2 * 24576];   // 2 ring slots x [A 8KB | B 16KB]
  const int t = threadIdx.x;
  const int lane = t & 63, wid = t >> 6;
  const int wr = wid >> 2, wc = wid & 3;        // 2 x 4 wave grid
  const int lr = lane & 15, lg = lane >> 4;

  const int nq = B / BM;                 // 16
  const int nk = (N + BN - 1) / BN;      // 391
  const int nwg = nq * nk;               // 6256 (divisible by 8)
  const int bid = blockIdx.x;
  // bijective XCD chunk swizzle (m204)
  const int qq = nwg >> 3, rr = nwg & 7;
  const int xcd = bid & 7, idx = bid >> 3;
  const int swz = (xcd < rr ? xcd * (qq + 1) : rr * (qq + 1) + (xcd - rr) * qq) + idx;
  const int qt = swz % nq, ktile = swz / nq;
  const int qbase = qt * BM;
  const int tile = ktile * BN;

  // --- staging precompute: linear LDS byte -> (logical row, chunk) ---
  const char* gA1; int ldA1;
  {
    int lb = t * 16;
    int R = lb >> 7, s = (lb >> 4) & 7;
    int cr = s ^ (R & 7);
    int r = 2 * R + ((cr >> 2) & 1);
    int c = cr & 3;
    gA1 = (const char*)qi8 + (size_t)(qbase + r) * D + c * 16;
    ldA1 = wid * 1024;                   // + slot*24576
  }
  const char* gB[2]; int ldB[2];
  #pragma unroll
  for (int j = 0; j < 2; ++j) {
    int lb = j * 8192 + t * 16;
    int R = lb >> 7, s = (lb >> 4) & 7;
    int cr = s ^ (R & 7);
    int r = 2 * R + ((cr >> 2) & 1);     // 0..255
    int c = cr & 3;
    gB[j] = (const char*)ki8 + (size_t)min(tile + r, N - 1) * D + c * 16;
    ldB[j] = 8192 + j * 8192 + wid * 1024;   // + slot*24576
  }

  const int laneByte = (lr >> 1) * 128 + (((lg + 4 * (lr & 1)) ^ ((lr >> 1) & 7)) * 16);
  const int aWaveOff = wr * 4096;          // + m*1024
  const int bWaveOff = 8192 + wc * 4096;   // + n*1024

  i32x4 acc[4][4];
  #pragma unroll
  for (int m = 0; m < 4; ++m)
    #pragma unroll
    for (int n = 0; n < 4; ++n) acc[m][n] = (i32x4)0;

  auto STAGE = [&](int u, int slot) {   // one unit (K=64): 3 gloads/thread
    const int off = u * 64;
    const int dbase = slot * 24576;
    __builtin_amdgcn_global_load_lds((as1_uint*)(const void*)(gA1 + off),
                                     (as3_uint*)(void*)(lds + dbase + ldA1), 16, 0, 0);
    #pragma unroll
    for (int j = 0; j < 2; ++j)
      __builtin_amdgcn_global_load_lds((as1_uint*)(const void*)(gB[j] + off),
                                       (as3_uint*)(void*)(lds + dbase + ldB[j]), 16, 0, 0);
  };

  STAGE(0, 0);                           // prologue

  #pragma unroll 1
  for (int u = 0; u < 8; ++u) {        // 8 phases, K=64 each
    const int slot = u & 1;
    __syncthreads();                   // free wait: unit u issued a phase ago
    STAGE((u + 1) & 7, slot ^ 1);      // u=7 dummy-stages unit 0
    const char* abase = lds + slot * 24576 + aWaveOff + laneByte;
    const char* bbase = lds + slot * 24576 + bWaveOff + laneByte;
    i32x4 a[4], b[4];
    #pragma unroll
    for (int m = 0; m < 4; ++m) a[m] = *(const i32x4*)(abase + m * 1024);
    #pragma unroll
    for (int n = 0; n < 4; ++n) b[n] = *(const i32x4*)(bbase + n * 1024);
    __builtin_amdgcn_s_setprio(1);
    #pragma unroll
    for (int m = 0; m < 4; ++m)
      #pragma unroll
      for (int n = 0; n < 4; ++n)
        acc[m][n] = __builtin_amdgcn_mfma_i32_16x16x64_i8(a[m], b[n], acc[m][n], 0, 0, 0);
    __builtin_amdgcn_s_setprio(0);
  }

  // ---- epilogue: dequant + two-level compaction of sims >= TAU ----
  __syncthreads();   // drains vmcnt(0) before LDS reuse
  unsigned int* rowcnt = (unsigned int*)lds;                 // 128 x u32
  float2* rowlist = (float2*)(lds + 1024);                   // 128 x 16 x 8B (16KB)
  float* sQl = (float*)(lds + 1024 + 16384);                 // 128 floats
  float* sKl = (float*)(lds + 1024 + 16384 + 512);           // 256 floats
  if (t < BM) { rowcnt[t] = 0; sQl[t] = sq[qbase + t]; }
  if (t >= 256) sKl[t - 256] = sk[min(tile + t - 256, N - 1)];
  __syncthreads();
  // C/D layout: col=lane&15 (lr), row=(lane>>4)*4+reg (lg*4+j)
  float skv[4];
  #pragma unroll
  for (int n = 0; n < 4; ++n) skv[n] = sKl[wc * 64 + n * 16 + lr];
  #pragma unroll
  for (int m = 0; m < 4; ++m) {
    #pragma unroll
    for (int j = 0; j < 4; ++j) {
      int rl = wr * 64 + m * 16 + lg * 4 + j;   // local query row 0..127
      const float sqv = sQl[rl];
      #pragma unroll
      for (int n = 0; n < 4; ++n) {
        int cl = wc * 64 + n * 16 + lr;         // local key col 0..255
        float v = (float)acc[m][n][j] * (sqv * skv[n]);
        int kg = tile + cl;
        if (v >= TAU && kg < N) {
          unsigned int p = atomicAdd(&rowcnt[rl], 1u);
          if (p < ROWSLOTS) {
            float2 e; e.x = v; e.y = __int_as_float(kg);
            rowlist[rl * ROWSLOTS + p] = e;
          }
        }
      }
    }
  }
  __syncthreads();
  if (t < BM) {
    unsigned int cnt = rowcnt[t];
    if (cnt > ROWSLOTS) cnt = ROWSLOTS;
    if (cnt) {
      int qg = qbase + t;
      int pos = atomicAdd(&gcnt[qg], (int)cnt);
      #pragma unroll 1
      for (unsigned int i = 0; i < cnt; ++i) {
        if (pos + (int)i < CAP)
          *(float2*)&cand[((size_t)qg * CAP + pos + i) * 2] = rowlist[t * ROWSLOTS + i];
      }
    }
  }
}

// ---------- Kernel 3: threshold-select -> exact rescore -> output -----------
// Latency polish vs R14: value-gather unrolled x8 (16 independent loads in
// flight vs 1; was ~unroll-1 dependent-chain at ~200-400cy/iter), rescore
// unrolled x2, binary search wcnt double-buffered (13 barriers vs 24).
// Selection logic unchanged -> outputs identical.
__global__ __launch_bounds__(256)
void k_merge_rescore(const float* __restrict__ cand, const int* __restrict__ gcnt,
                     const float* __restrict__ queries, const float* __restrict__ keys,
                     const float* __restrict__ values,
                     const float* __restrict__ inv_nq, const float* __restrict__ inv_nk,
                     float* __restrict__ out, int B, int N) {
  __shared__ float cv[CAP]; __shared__ int ci[CAP];
  __shared__ float qrow[D];
  __shared__ int wcnt[2][4];
  __shared__ int sel[SELMAX]; __shared__ float exacts[SELMAX];
  __shared__ unsigned int selcnt;
  __shared__ float topv[KSEL]; __shared__ int topi[KSEL];
  __shared__ float wts[KSEL]; __shared__ float inv_sum_s;
  const int t = threadIdx.x, lane = t & 63, wid = t >> 6;
  const int q = blockIdx.x;
  const int cnt = min(gcnt[q], CAP);
  for (int p = t; p < D; p += 256) qrow[p] = queries[(size_t)q * D + p];
  for (int p = t; p < cnt; p += 256) {
    float2 e = *(const float2*)&cand[((size_t)q * CAP + p) * 2];
    cv[p] = e.x; ci[p] = __float_as_int(e.y);
  }
  if (t == 0) selcnt = 0u;
  __syncthreads();
  // threshold binary search (all threads follow identical lo/hi trajectory)
  float thr = -FLT_MAX;
  if (cnt > TSEL) {
    float lo = TAU, hi = 1.03f;
    #pragma unroll 1
    for (int it = 0; it < 12; ++it) {
      float mid = 0.5f * (lo + hi);
      int c = 0;
      for (int p = t; p < cnt; p += 256) c += (cv[p] >= mid);
      #pragma unroll
      for (int off = 32; off; off >>= 1) c += __shfl_xor(c, off);
      if (lane == 0) wcnt[it & 1][wid] = c;
      __syncthreads();   // double-buffered wcnt: one barrier per iteration
      int tot = wcnt[it & 1][0] + wcnt[it & 1][1] + wcnt[it & 1][2] + wcnt[it & 1][3];
      if (tot >= TSEL) lo = mid; else hi = mid;
    }
    thr = lo;
  }
  __syncthreads();
  // collect candidate set >= thr
  for (int p = t; p < cnt; p += 256) {
    if (cv[p] >= thr) {
      unsigned int s = atomicAdd(&selcnt, 1u);
      if (s < SELMAX) sel[s] = ci[p];
    }
  }
  __syncthreads();
  const int M = min((int)selcnt, SELMAX);
  // exact fp32 rescore of all M rows (wave-per-row, 2 rows' loads in flight)
  const float invq = inv_nq[q];
  #pragma unroll 2
  for (int j = wid; j < M; j += 4) {
    int idx = sel[j];
    const float4* kr = (const float4*)(keys + (size_t)idx * D);
    float4 k0 = kr[lane * 2], k1 = kr[lane * 2 + 1];
    float4 q0 = *(const float4*)&qrow[lane * 8];
    float4 q1 = *(const float4*)&qrow[lane * 8 + 4];
    float dotv = q0.x*k0.x + q0.y*k0.y + q0.z*k0.z + q0.w*k0.w
               + q1.x*k1.x + q1.y*k1.y + q1.z*k1.z + q1.w*k1.w;
    #pragma unroll
    for (int off = 32; off; off >>= 1) dotv += __shfl_xor(dotv, off);
    if (lane == 0) exacts[j] = dotv * invq * inv_nk[idx];
  }
  __syncthreads();
  // exact sorted top-32 from M (<=128): wave 0, 2 values/lane
  if (wid == 0) {
    float v0 = (lane < M) ? exacts[lane] : -FLT_MAX;
    float v1 = (lane + 64 < M) ? exacts[lane + 64] : -FLT_MAX;
    const int p0 = lane, p1 = lane + 64;
    for (int r = 0; r < KSEL; ++r) {
      float bv; int bp;
      if (v0 >= v1) { bv = v0; bp = p0; } else { bv = v1; bp = p1; }
      #pragma unroll
      for (int off = 32; off; off >>= 1) {
        float ov = __shfl_xor(bv, off); int op = __shfl_xor(bp, off);
        if (ov > bv || (ov == bv && op < bp)) { bv = ov; bp = op; }
      }
      if (lane == 0) { topv[r] = bv; topi[r] = sel[bp]; }
      if (p0 == bp) v0 = -FLT_MAX;
      if (p1 == bp) v1 = -FLT_MAX;
    }
  }
  __syncthreads();
  if (t == 0) {
    float mx = topv[0], sum = 0.f;
    for (int r = 0; r < KSEL; ++r) { float w = expf(topv[r] - mx); wts[r] = w; sum += w; }
    inv_sum_s = 1.0f / sum;
  }
  __syncthreads();
  const float inv_sum = inv_sum_s;
  float a0 = 0.f, a1 = 0.f;
  // value gather: unroll x8 -> 16 independent global loads in flight
  #pragma unroll 8
  for (int r = 0; r < KSEL; ++r) {
    const float* vr = values + (size_t)topi[r] * VDIM;
    float w = wts[r];
    a0 += w * vr[t]; a1 += w * vr[t + 256];
  }
  out[(size_t)q * VDIM + t] = a0 * inv_sum;
  out[(size_t)q * VDIM + t + 256] = a1 * inv_sum;
  if (t < KSEL) out[(size_t)B * VDIM + (size_t)q * KSEL + t] = topv[t];
}

extern "C" void kernel_launch(void* const* d_in, const int* in_sizes, int n_in,
                              void* d_out, int out_size, void* d_ws, size_t ws_size,
                              hipStream_t stream) {
  const float* queries = (const float*)d_in[0];
  const float* keys    = (const float*)d_in[1];
  const float* values  = (const float*)d_in[2];
  const int B = in_sizes[0] / D;     // 2048
  const int N = in_sizes[1] / D;     // 100000
  char* ws = (char*)d_ws;
  size_t o = 0;
  signed char* ki8 = (signed char*)(ws + o); o += (size_t)N * D; o = (o + 255) & ~(size_t)255;
  signed char* qi8 = (signed char*)(ws + o); o += (size_t)B * D; o = (o + 255) & ~(size_t)255;
  float* inv_nk = (float*)(ws + o); o += (size_t)N * 4; o = (o + 255) & ~(size_t)255;
  float* inv_nq = (float*)(ws + o); o += (size_t)B * 4; o = (o + 255) & ~(size_t)255;
  float* sk     = (float*)(ws + o); o += (size_t)N * 4; o = (o + 255) & ~(size_t)255;
  float* sq     = (float*)(ws + o); o += (size_t)B * 4; o = (o + 255) & ~(size_t)255;
  int*   gcnt   = (int*)(ws + o);   o += (size_t)B * 4; o = (o + 255) & ~(size_t)255;
  float* cand   = (float*)(ws + o); o += (size_t)B * CAP * 8;
  float* out = (float*)d_out;

  hipMemsetAsync(gcnt, 0, B * sizeof(int), stream);
  k_prep<<<(N + B + 3) / 4, 256, 0, stream>>>(queries, keys, qi8, ki8,
                                              inv_nq, inv_nk, sq, sk, B, N);
  const int nq = B / BM, nk = (N + BN - 1) / BN;
  k_gemm_filter<<<nq * nk, 512, 0, stream>>>(qi8, ki8, sq, sk, cand, gcnt, B, N);
  k_merge_rescore<<<B, 256, 0, stream>>>(cand, gcnt, queries, keys, values,
                                         inv_nq, inv_nk, out, B, N);
}